// Round 14
// baseline (91.928 us; speedup 1.0000x reference)
//
#include <hip/hip_runtime.h>
#include <math.h>

namespace {
constexpr int NB = 16, NP = 2048, KNN = 32, CH1 = 6, CH2 = 32;
constexpr int QPB = 16;                 // queries per block (8 waves x 2 phases)
constexpr int NBLK = NB * NP / QPB;     // 2048 knn blocks
constexpr float BN_EPS = 1e-5f;

// workspace byte offsets
constexpr size_t OFF_S1REP   = 0;      // double[8][12] replicated BN1 accum (768 B)
constexpr size_t OFF_STATS2L = 768;    // double[4][27] BN2 moment accum (864 B)
constexpr size_t OFF_SC1     = 1664;   // float[12]
constexpr size_t OFF_P       = 2048;                                // float[NB*NP*6]
constexpr size_t OFF_MINQ    = OFF_P + sizeof(float)*NB*NP*CH1;     // float[NB*NP*6]
}

typedef __attribute__((ext_vector_type(2))) float f32x2;

// packed fp32 (VOP3P, per-half IEEE RN — bit-identical to scalar mul/add)
__device__ __forceinline__ f32x2 pk_mul(f32x2 a, f32x2 b) {
  f32x2 d; asm("v_pk_mul_f32 %0, %1, %2" : "=v"(d) : "v"(a), "v"(b)); return d;
}
__device__ __forceinline__ f32x2 pk_add(f32x2 a, f32x2 b) {
  f32x2 d; asm("v_pk_add_f32 %0, %1, %2" : "=v"(d) : "v"(a), "v"(b)); return d;
}

// ---------------- DPP wave-64 reductions (VALU pipe, no LDS) ----------------
template <int C> __device__ __forceinline__ int dpp0i(int x) {
  return __builtin_amdgcn_update_dpp(0, x, C, 0xf, 0xf, true);
}
template <int C> __device__ __forceinline__ float dpp0f(float x) {
  return __uint_as_float((unsigned)__builtin_amdgcn_update_dpp(
      0, (int)__float_as_uint(x), C, 0xf, 0xf, true));
}
template <int C> __device__ __forceinline__ float dppInff(float x) {
  return __uint_as_float((unsigned)__builtin_amdgcn_update_dpp(
      0x7F800000, (int)__float_as_uint(x), C, 0xf, 0xf, false));
}
__device__ __forceinline__ int wave_isum_bcast(int x) {
  x += dpp0i<0x111>(x); x += dpp0i<0x112>(x); x += dpp0i<0x114>(x);
  x += dpp0i<0x118>(x); x += dpp0i<0x142>(x); x += dpp0i<0x143>(x);
  return __builtin_amdgcn_readlane(x, 63);
}
__device__ __forceinline__ float wave_fsum63(float x) {
  x += dpp0f<0x111>(x); x += dpp0f<0x112>(x); x += dpp0f<0x114>(x);
  x += dpp0f<0x118>(x); x += dpp0f<0x142>(x); x += dpp0f<0x143>(x);
  return x;
}
__device__ __forceinline__ float wave_fmin63(float x) {
  x = fminf(x, dppInff<0x111>(x)); x = fminf(x, dppInff<0x112>(x));
  x = fminf(x, dppInff<0x114>(x)); x = fminf(x, dppInff<0x118>(x));
  x = fminf(x, dppInff<0x142>(x)); x = fminf(x, dppInff<0x143>(x));
  return x;
}

#define BSEL(m, x, y) ((((x)) & (m)) | (((y)) & ~(m)))  // -> v_bfi

// Single-bit radix round.
#define RROUND(alive, below, rem, ca, plane)                  \
  { unsigned z_ = BSEL((plane), 0u, (alive));                 \
    int c_ = wave_isum_bcast(__popc(z_));                     \
    if (c_ >= (rem)) { alive = z_; ca = c_; }                 \
    else { rem -= c_; below |= z_; alive &= (plane); ca -= c_; } }

// finish a 16-reg packed half: J8,4,2,1 -> a[i] = plane of its bit i (MSB first)
#define TR16(a)                                                      \
  _Pragma("unroll") for (int g_ = 0; g_ < 8; ++g_) {                 \
    unsigned hi_ = a[g_], lo_ = a[g_+8];                             \
    a[g_]   = __builtin_amdgcn_perm(hi_, lo_, 0x07030501u);          \
    a[g_+8] = __builtin_amdgcn_perm(hi_, lo_, 0x06020400u); }        \
  _Pragma("unroll") for (int g_ = 0; g_ < 8; ++g_) {                 \
    int k_ = (g_ >> 2)*8 + (g_ & 3);                                 \
    unsigned A_ = a[k_], B_ = a[k_+4];                               \
    a[k_]   = BSEL(0x0F0F0F0Fu, B_ >> 4, A_);                        \
    a[k_+4] = BSEL(0xF0F0F0F0u, A_ << 4, B_); }                      \
  _Pragma("unroll") for (int g_ = 0; g_ < 8; ++g_) {                 \
    int k_ = (g_ >> 1)*4 + (g_ & 1);                                 \
    unsigned A_ = a[k_], B_ = a[k_+2];                               \
    a[k_]   = BSEL(0x33333333u, B_ >> 2, A_);                        \
    a[k_+2] = BSEL(0xCCCCCCCCu, A_ << 2, B_); }                      \
  _Pragma("unroll") for (int g_ = 0; g_ < 8; ++g_) {                 \
    int k_ = g_*2;                                                   \
    unsigned A_ = a[k_], B_ = a[k_+1];                               \
    a[k_]   = BSEL(0x55555555u, B_ >> 1, A_);                        \
    a[k_+1] = BSEL(0xAAAAAAAAu, A_ << 1, B_); }

// Fused: pq + KNN select + per-query min(q) + BN1 replicated-atomic partials.
// r10's exact per-query body (best measured: 59.5us), wrapped in a 2-phase
// sequential loop: one staged tile + ONE barrier serves 16 queries. Phase 2
// runs barrier-free (LDS read-only) so waves de-phase -> the SIMD gets
// independent instruction streams at different pipeline phases.
__global__ __launch_bounds__(512, 6) void knn_kernel(const float* __restrict__ x,
                                                     const float* __restrict__ W1,
                                                     const float* __restrict__ b1,
                                                     float* __restrict__ pout,
                                                     float* __restrict__ minq,
                                                     double* __restrict__ s1rep) {
  __shared__ float4 XC[512], YC[512], ZC[512], WC[512];  // 32 KiB chunked SoA
  __shared__ float red[12][8];
  const int lane  = threadIdx.x & 63;
  const int w     = threadIdx.x >> 6;
  const int qbase = blockIdx.x * QPB;      // 16 | 2048 -> same batch per block
  const int b     = qbase >> 11;

  const float* xb = x + (size_t)b * NP * 3;
  {
    const int t = threadIdx.x;               // slot t: points 256*(t>>6)+64k+(t&63)
    const int g0 = t >> 6, ls = t & 63;
    float xx[4], yy[4], zz[4], ww[4];
#pragma unroll
    for (int k = 0; k < 4; ++k) {
      const float* pp = xb + (g0*256 + k*64 + ls) * 3;
      float a0 = pp[0], a1 = pp[1], a2 = pp[2];
      xx[k] = a0; yy[k] = a1; zz[k] = a2;
      ww[k] = __fadd_rn(__fadd_rn(__fmul_rn(a0,a0), __fmul_rn(a1,a1)), __fmul_rn(a2,a2));
    }
    XC[t] = (float4){xx[0], xx[1], xx[2], xx[3]};
    YC[t] = (float4){yy[0], yy[1], yy[2], yy[3]};
    ZC[t] = (float4){zz[0], zz[1], zz[2], zz[3]};
    WC[t] = (float4){ww[0], ww[1], ww[2], ww[3]};
  }
  __syncthreads();

  const float* Xs = (const float*)XC;
  const float* Ys = (const float*)YC;
  const float* Zs = (const float*)ZC;
  const float* Ws = (const float*)WC;

  float hsAcc[CH1], hqAcc[CH1];   // BN1 partials across phases (valid at lane 63)
#pragma unroll
  for (int c = 0; c < CH1; ++c) { hsAcc[c] = 0.f; hqAcc[c] = 0.f; }

#pragma unroll 1
  for (int ph = 0; ph < 2; ++ph) {
    const int qi = qbase + ph * 8 + w;
    const int n  = qi & (NP - 1);

    // query coords (wave-uniform broadcast reads); point n -> v=n>>6, lane=n&63
    const int vq = n >> 6, lq = n & 63;
    const int qidx = (((vq >> 2) << 6) | lq) * 4 + (vq & 3);
    const float qx = Xs[qidx], qy = Ys[qidx], qz = Zs[qidx], qw = Ws[qidx];
    const f32x2 qx2 = {qx,qx}, qy2 = {qy,qy}, qz2 = {qz,qz}, qw2 = {qw,qw};

    // distances, bit-exact vs reference ((x*x+y*y)+z*z ; (sqi+sqj) - (dot+dot)).
    // All d >= 0 so raw float bits order. dd[31-v] = candidate v*64+lane.
    unsigned dd[32];
#pragma unroll
    for (int g = 0; g < 8; ++g) {
      const int cs = g*64 + lane;
      float4 X = XC[cs], Y = YC[cs], Z = ZC[cs], Wv = WC[cs];
      f32x2 x01 = {X.x,X.y}, y01 = {Y.x,Y.y}, z01 = {Z.x,Z.y}, w01 = {Wv.x,Wv.y};
      f32x2 x23 = {X.z,X.w}, y23 = {Y.z,Y.w}, z23 = {Z.z,Z.w}, w23 = {Wv.z,Wv.w};
      f32x2 dotA = pk_add(pk_add(pk_mul(qx2,x01), pk_mul(qy2,y01)), pk_mul(qz2,z01));
      f32x2 dotB = pk_add(pk_add(pk_mul(qx2,x23), pk_mul(qy2,y23)), pk_mul(qz2,z23));
      f32x2 ssA = pk_add(qw2, w01), ssB = pk_add(qw2, w23);
      f32x2 dA = pk_add(dotA, dotA), dB = pk_add(dotB, dotB);
      dd[31-(4*g+0)] = __float_as_uint(__fsub_rn(ssA.x, dA.x));
      dd[31-(4*g+1)] = __float_as_uint(__fsub_rn(ssA.y, dA.y));
      dd[31-(4*g+2)] = __float_as_uint(__fsub_rn(ssB.x, dB.x));
      dd[31-(4*g+3)] = __float_as_uint(__fsub_rn(ssB.y, dB.y));
    }

    // J=16 stage produces BOTH packed halves; dd dies here.
    unsigned h[16], l[16];
#pragma unroll
    for (int g = 0; g < 16; ++g) {
      h[g] = __builtin_amdgcn_perm(dd[g], dd[g+16], 0x07060302u);
      l[g] = __builtin_amdgcn_perm(dd[g], dd[g+16], 0x05040100u);
    }
    TR16(h);   // h[i] = plane of distance bit (31-i)

    // radix select on bits 30..16; SALU alive-count; guards from round 7
    unsigned alive = 0xFFFFFFFFu, below = 0u;
    int rem = KNN, ca = 2048;
#pragma unroll
    for (int i = 1; i <= 6; ++i) {
      RROUND(alive, below, rem, ca, h[i]);
    }
#pragma unroll
    for (int i = 7; i <= 15; ++i) {
      if (ca != rem) RROUND(alive, below, rem, ca, h[i]);
    }
    unsigned sel;
    if (__builtin_expect(ca == rem, 1)) {
      sel = below | alive;
    } else {
      TR16(l);  // l[i] = plane of distance bit (15-i)
#pragma unroll
      for (int i = 0; i < 16; ++i) {
        if (ca != rem) RROUND(alive, below, rem, ca, l[i]);
      }
      sel = below;
      if (ca == rem) {
        sel |= alive;
      } else {
        // bit-identical distances: smallest j = v*64 + lane -> v-major order
        for (int v = 0; v < 32; ++v) {
          if (rem <= 0) break;
          bool mine = (alive >> v) & 1;
          unsigned long long mb = __ballot(mine);
          int c = __popcll(mb);
          if (c <= rem) { if (mine) sel |= 1u << v; rem -= c; }
          else {
            if (mine && (int)__popcll(mb & ((1ull << lane) - 1)) < rem) sel |= 1u << v;
            rem = 0;
          }
        }
      }
    }

    // gather: sum/sumsq/min of q_j over selected (scalar chunk reads)
    float w3[CH1], w4[CH1], w5[CH1];
#pragma unroll
    for (int c = 0; c < CH1; ++c) { w3[c]=W1[3*CH1+c]; w4[c]=W1[4*CH1+c]; w5[c]=W1[5*CH1+c]; }
    float sq_[CH1], sqq[CH1], mn[CH1];
#pragma unroll
    for (int c = 0; c < CH1; ++c) { sq_[c] = 0.f; sqq[c] = 0.f; mn[c] = INFINITY; }
    unsigned m = sel;
    while (m) {
      int v = __builtin_ctz(m); m &= m - 1;
      int idx = (((v >> 2) << 6) | lane) * 4 + (v & 3);
      float px_ = Xs[idx], py_ = Ys[idx], pz_ = Zs[idx];
#pragma unroll
      for (int c = 0; c < CH1; ++c) {
        float qv = px_*w3[c] + py_*w4[c] + pz_*w5[c];   // contraction OK here
        sq_[c] += qv; sqq[c] += qv*qv; mn[c] = fminf(mn[c], qv);
      }
    }

    // p_i for this query (uniform across lanes)
    float pv[CH1];
#pragma unroll
    for (int c = 0; c < CH1; ++c) {
      float qv = qx*w3[c] + qy*w4[c] + qz*w5[c];
      pv[c] = b1[c] + qx*W1[c] + qy*W1[CH1+c] + qz*W1[2*CH1+c] + qv;
    }

#pragma unroll
    for (int c = 0; c < CH1; ++c) {
      float s  = wave_fsum63(sq_[c]);
      float s2 = wave_fsum63(sqq[c]);
      float mm = wave_fmin63(mn[c]);
      if (lane == 63) {
        minq[qi*CH1 + c] = mm;
        hsAcc[c] += fmaf(32.f, pv[c], -s);                              // sum_k (p-q)
        hqAcc[c] += fmaf(32.f, pv[c]*pv[c], fmaf(-2.f*pv[c], s, s2));   // sum_k (p-q)^2
      }
    }
    if (lane == 0) {
#pragma unroll
      for (int c = 0; c < CH1; ++c) pout[qi*CH1 + c] = pv[c];
    }
  }

  if (lane == 63) {
#pragma unroll
    for (int c = 0; c < CH1; ++c) { red[c][w] = hsAcc[c]; red[CH1 + c][w] = hqAcc[c]; }
  }
  __syncthreads();
  if (threadIdx.x < 12) {
    float s = 0.f;
#pragma unroll
    for (int ww2 = 0; ww2 < 8; ++ww2) s += red[threadIdx.x][ww2];
    atomicAdd(s1rep + (blockIdx.x & 7) * 12 + threadIdx.x, (double)s);
  }
}

// stage2: derive sc1 (block 0 publishes), compute me per query, accumulate the
// 27 BN2 moments (Sme[6] + upper-tri M[21]); y-stats derive from them linearly.
__global__ __launch_bounds__(256) void stage2_kernel(const float* __restrict__ p,
                                                     const float* __restrict__ minq,
                                                     const double* __restrict__ s1rep,
                                                     const float* __restrict__ gamma1,
                                                     const float* __restrict__ beta1,
                                                     float* __restrict__ sc1g,
                                                     double* __restrict__ stats2L) {
  __shared__ double tot1[12];
  __shared__ float sc1s[12];
  __shared__ float acc[4][27];
  const int t = threadIdx.x;
  if (t < 12) {
    double s = 0.0;
#pragma unroll
    for (int r = 0; r < 8; ++r) s += s1rep[r*12 + t];
    tot1[t] = s;
  }
  __syncthreads();
  if (t < CH1) {
    double cnt  = (double)NB * NP * KNN;
    double mean = tot1[t] / cnt;
    double var  = tot1[CH1 + t] / cnt - mean * mean;
    float scale = gamma1[t] / sqrtf((float)var + BN_EPS);
    sc1s[t] = scale; sc1s[CH1 + t] = beta1[t] - (float)mean * scale;
  }
  __syncthreads();
  if (blockIdx.x == 0 && t < 12) sc1g[t] = sc1s[t];

  const int qi = blockIdx.x * 256 + t;
  const int w = t >> 6, lane = t & 63;
  float me[CH1];
#pragma unroll
  for (int c = 0; c < CH1; ++c) {
    float v = fmaf(sc1s[c], p[qi*CH1 + c] - minq[qi*CH1 + c], sc1s[CH1 + c]);
    me[c] = v > 0.f ? v : expm1f(v);
  }
  float vals[27];
#pragma unroll
  for (int c = 0; c < CH1; ++c) vals[c] = me[c];
  {
    int id = 6;
#pragma unroll
    for (int c = 0; c < CH1; ++c)
#pragma unroll
      for (int d = c; d < CH1; ++d) { vals[id] = me[c]*me[d]; ++id; }
  }
#pragma unroll
  for (int k = 0; k < 27; ++k) {
    float s = wave_fsum63(vals[k]);
    if (lane == 63) acc[w][k] = s;
  }
  __syncthreads();
  if (t < 27)
    atomicAdd(stats2L + (blockIdx.x & 3) * 27 + t,
              (double)((acc[0][t] + acc[1][t]) + (acc[2][t] + acc[3][t])));
}

// final: derive sc2 per block from the 27 moments, recompute y, BN2 + ELU.
__global__ __launch_bounds__(256) void out_kernel(const float* __restrict__ p,
                                                  const float* __restrict__ minq,
                                                  const float* __restrict__ sc1,
                                                  const float* __restrict__ W2,
                                                  const float* __restrict__ b2,
                                                  const double* __restrict__ stats2L,
                                                  const float* __restrict__ gamma2,
                                                  const float* __restrict__ beta2,
                                                  float* __restrict__ out) {
  __shared__ float m2[27];
  __shared__ float me_lds[8][CH1];
  __shared__ float s2s[CH2], s2h[CH2];
  const int t = threadIdx.x;
  if (t < 27)
    m2[t] = (float)(((stats2L[t] + stats2L[27+t]) + (stats2L[54+t] + stats2L[81+t])));
  const int qbase = blockIdx.x * 8;
  if (t >= 64 && t < 112) {
    int qs = (t - 64) / 6, c = (t - 64) % 6;
    int qi = qbase + qs;
    float v = fmaf(sc1[c], p[qi*CH1 + c] - minq[qi*CH1 + c], sc1[CH1 + c]);
    me_lds[qs][c] = v > 0.f ? v : expm1f(v);
  }
  __syncthreads();
  if (t < CH2) {
    float wv[CH1];
#pragma unroll
    for (int c = 0; c < CH1; ++c) wv[c] = W2[c*CH2 + t];
    float sy = 0.f;
#pragma unroll
    for (int c = 0; c < CH1; ++c) sy = fmaf(wv[c], m2[c], sy);
    float sy2 = 0.f;
    {
      int id = 6;
#pragma unroll
      for (int c = 0; c < CH1; ++c)
#pragma unroll
        for (int d = c; d < CH1; ++d) {
          float coef = (c == d) ? wv[c]*wv[c] : 2.f*wv[c]*wv[d];
          sy2 = fmaf(coef, m2[id], sy2); ++id;
        }
    }
    const double N = (double)NB * NP;
    double bo   = (double)b2[t];
    double mean = ((double)sy + N*bo) / N;
    double Ey2  = ((double)sy2 + 2.0*bo*(double)sy + N*bo*bo) / N;
    double var  = Ey2 - mean*mean;
    float scale = gamma2[t] / sqrtf((float)var + BN_EPS);
    s2s[t] = scale; s2h[t] = beta2[t] - (float)mean * scale;
  }
  __syncthreads();
  const int qs = t >> 5, o = t & 31;
  const int qi = qbase + qs;
  float y = b2[o];
#pragma unroll
  for (int c = 0; c < CH1; ++c) y = fmaf(me_lds[qs][c], W2[c*CH2 + o], y);
  float r = fmaf(s2s[o], y, s2h[o]);
  out[(size_t)qi*CH2 + o] = r > 0.f ? r : expm1f(r);
}

extern "C" void kernel_launch(void* const* d_in, const int* in_sizes, int n_in,
                              void* d_out, int out_size, void* d_ws, size_t ws_size,
                              hipStream_t stream) {
  const float* x      = (const float*)d_in[0];
  const float* W1     = (const float*)d_in[1];
  const float* b1     = (const float*)d_in[2];
  const float* gamma1 = (const float*)d_in[3];
  const float* beta1  = (const float*)d_in[4];
  const float* W2     = (const float*)d_in[5];
  const float* b2     = (const float*)d_in[6];
  const float* gamma2 = (const float*)d_in[7];
  const float* beta2  = (const float*)d_in[8];
  float* out = (float*)d_out;
  char* ws = (char*)d_ws;

  double* s1rep   = (double*)(ws + OFF_S1REP);
  double* stats2L = (double*)(ws + OFF_STATS2L);
  float* sc1  = (float*)(ws + OFF_SC1);
  float* p    = (float*)(ws + OFF_P);
  float* minq = (float*)(ws + OFF_MINQ);

  hipMemsetAsync(ws, 0, 1664, stream);  // zero BN stat accumulators

  knn_kernel   <<<dim3(NBLK),       dim3(512), 0, stream>>>(x, W1, b1, p, minq, s1rep);
  stage2_kernel<<<dim3(NB*NP/256),  dim3(256), 0, stream>>>(p, minq, s1rep, gamma1, beta1,
                                                            sc1, stats2L);
  out_kernel   <<<dim3(NB*NP/8),    dim3(256), 0, stream>>>(p, minq, sc1, W2, b2,
                                                            stats2L, gamma2, beta2, out);
}

// Round 15
// 71.906 us; speedup vs baseline: 1.2784x; 1.2784x over previous
//
#include <hip/hip_runtime.h>
#include <math.h>

namespace {
constexpr int NB = 16, NP = 2048, KNN = 32, CH1 = 6, CH2 = 32;
constexpr int QPB = 8;                  // queries (waves) per knn block
constexpr int NBLK = NB * NP / QPB;     // 4096 knn blocks
constexpr float BN_EPS = 1e-5f;

// workspace byte offsets
constexpr size_t OFF_S1REP   = 0;      // double[8][12] replicated BN1 accum (768 B)
constexpr size_t OFF_STATS2L = 768;    // double[4][27] BN2 moment accum (864 B)
constexpr size_t OFF_SC1     = 1664;   // float[12]
constexpr size_t OFF_P       = 2048;                                // float[NB*NP*6]
constexpr size_t OFF_MINQ    = OFF_P + sizeof(float)*NB*NP*CH1;     // float[NB*NP*6]
}

typedef __attribute__((ext_vector_type(2))) float f32x2;

// packed fp32 (VOP3P, per-half IEEE RN — bit-identical to scalar mul/add)
__device__ __forceinline__ f32x2 pk_mul(f32x2 a, f32x2 b) {
  f32x2 d; asm("v_pk_mul_f32 %0, %1, %2" : "=v"(d) : "v"(a), "v"(b)); return d;
}
__device__ __forceinline__ f32x2 pk_add(f32x2 a, f32x2 b) {
  f32x2 d; asm("v_pk_add_f32 %0, %1, %2" : "=v"(d) : "v"(a), "v"(b)); return d;
}

// ---------------- DPP wave-64 reductions (VALU pipe, no LDS) ----------------
template <int C> __device__ __forceinline__ int dpp0i(int x) {
  return __builtin_amdgcn_update_dpp(0, x, C, 0xf, 0xf, true);
}
template <int C> __device__ __forceinline__ float dpp0f(float x) {
  return __uint_as_float((unsigned)__builtin_amdgcn_update_dpp(
      0, (int)__float_as_uint(x), C, 0xf, 0xf, true));
}
template <int C> __device__ __forceinline__ float dppInff(float x) {
  return __uint_as_float((unsigned)__builtin_amdgcn_update_dpp(
      0x7F800000, (int)__float_as_uint(x), C, 0xf, 0xf, false));
}
__device__ __forceinline__ int wave_isum_bcast(int x) {
  x += dpp0i<0x111>(x); x += dpp0i<0x112>(x); x += dpp0i<0x114>(x);
  x += dpp0i<0x118>(x); x += dpp0i<0x142>(x); x += dpp0i<0x143>(x);
  return __builtin_amdgcn_readlane(x, 63);
}
__device__ __forceinline__ float wave_fsum63(float x) {
  x += dpp0f<0x111>(x); x += dpp0f<0x112>(x); x += dpp0f<0x114>(x);
  x += dpp0f<0x118>(x); x += dpp0f<0x142>(x); x += dpp0f<0x143>(x);
  return x;
}
__device__ __forceinline__ float wave_fmin63(float x) {
  x = fminf(x, dppInff<0x111>(x)); x = fminf(x, dppInff<0x112>(x));
  x = fminf(x, dppInff<0x114>(x)); x = fminf(x, dppInff<0x118>(x));
  x = fminf(x, dppInff<0x142>(x)); x = fminf(x, dppInff<0x143>(x));
  return x;
}

#define BSEL(m, x, y) ((((x)) & (m)) | (((y)) & ~(m)))  // -> v_bfi

// Fused: pq + KNN select + per-query min(q) + BN1 replicated-atomic partials.
// One WAVE per query. Candidate mapping j = v*64 + lane. Single chunked-SoA
// LDS layout: XC[s=g*64+lane] = float4 of x-coords of points {256g+64k+lane}.
// All LDS access patterns conflict-free (measured 206K residual only).
// (512,6) is the proven no-spill register configuration (40 VGPR).
__global__ __launch_bounds__(512, 6) void knn_kernel(const float* __restrict__ x,
                                                     const float* __restrict__ W1,
                                                     const float* __restrict__ b1,
                                                     float* __restrict__ pout,
                                                     float* __restrict__ minq,
                                                     double* __restrict__ s1rep) {
  __shared__ float4 XC[512], YC[512], ZC[512], WC[512];  // 32 KiB chunked SoA
  __shared__ float red[12][QPB];
  const int lane = threadIdx.x & 63;
  const int w    = threadIdx.x >> 6;
  const int qi   = blockIdx.x * QPB + w;   // 8 | 2048 -> same batch per block
  const int b    = qi >> 11;
  const int n    = qi & (NP - 1);

  const float* xb = x + (size_t)b * NP * 3;
  {
    const int t = threadIdx.x;               // slot t: points 256*(t>>6)+64k+(t&63)
    const int g0 = t >> 6, ls = t & 63;
    float xx[4], yy[4], zz[4], ww[4];
#pragma unroll
    for (int k = 0; k < 4; ++k) {
      const float* pp = xb + (g0*256 + k*64 + ls) * 3;
      float a0 = pp[0], a1 = pp[1], a2 = pp[2];
      xx[k] = a0; yy[k] = a1; zz[k] = a2;
      ww[k] = __fadd_rn(__fadd_rn(__fmul_rn(a0,a0), __fmul_rn(a1,a1)), __fmul_rn(a2,a2));
    }
    XC[t] = (float4){xx[0], xx[1], xx[2], xx[3]};
    YC[t] = (float4){yy[0], yy[1], yy[2], yy[3]};
    ZC[t] = (float4){zz[0], zz[1], zz[2], zz[3]};
    WC[t] = (float4){ww[0], ww[1], ww[2], ww[3]};
  }
  __syncthreads();

  const float* Xs = (const float*)XC;
  const float* Ys = (const float*)YC;
  const float* Zs = (const float*)ZC;
  const float* Ws = (const float*)WC;

  // query coords (wave-uniform broadcast reads); point n -> v=n>>6, lane=n&63
  const int vq = n >> 6, lq = n & 63;
  const int qidx = (((vq >> 2) << 6) | lq) * 4 + (vq & 3);
  const float qx = Xs[qidx], qy = Ys[qidx], qz = Zs[qidx], qw = Ws[qidx];
  const f32x2 qx2 = {qx,qx}, qy2 = {qy,qy}, qz2 = {qz,qz}, qw2 = {qw,qw};

  // distances, bit-exact vs reference ((x*x+y*y)+z*z ; (sqi+sqj) - (dot+dot)).
  // All d >= 0 so raw float bits order. dd[31-v] = bits of candidate v*64+lane.
  unsigned dd[32];
#pragma unroll
  for (int g = 0; g < 8; ++g) {
    const int cs = g*64 + lane;              // base + compile-time offsets
    float4 X = XC[cs], Y = YC[cs], Z = ZC[cs], Wv = WC[cs];
    f32x2 x01 = {X.x,X.y}, y01 = {Y.x,Y.y}, z01 = {Z.x,Z.y}, w01 = {Wv.x,Wv.y};
    f32x2 x23 = {X.z,X.w}, y23 = {Y.z,Y.w}, z23 = {Z.z,Z.w}, w23 = {Wv.z,Wv.w};
    f32x2 dotA = pk_add(pk_add(pk_mul(qx2,x01), pk_mul(qy2,y01)), pk_mul(qz2,z01));
    f32x2 dotB = pk_add(pk_add(pk_mul(qx2,x23), pk_mul(qy2,y23)), pk_mul(qz2,z23));
    f32x2 ssA = pk_add(qw2, w01), ssB = pk_add(qw2, w23);
    f32x2 dA = pk_add(dotA, dotA), dB = pk_add(dotB, dotB);
    dd[31-(4*g+0)] = __float_as_uint(__fsub_rn(ssA.x, dA.x));
    dd[31-(4*g+1)] = __float_as_uint(__fsub_rn(ssA.y, dA.y));
    dd[31-(4*g+2)] = __float_as_uint(__fsub_rn(ssB.x, dB.x));
    dd[31-(4*g+3)] = __float_as_uint(__fsub_rn(ssB.y, dB.y));
  }

  // J=16 stage produces BOTH packed halves; dd dies here (32 regs live total).
  unsigned h[16], l[16];
#pragma unroll
  for (int g = 0; g < 16; ++g) {
    h[g] = __builtin_amdgcn_perm(dd[g], dd[g+16], 0x07060302u);
    l[g] = __builtin_amdgcn_perm(dd[g], dd[g+16], 0x05040100u);
  }
  // finish hi-half transpose: J8,4,2,1 on h -> h[i] = plane of bit (31-i)
#pragma unroll
  for (int g = 0; g < 8; ++g) {      // J=8
    unsigned hi = h[g], lo = h[g+8];
    h[g]   = __builtin_amdgcn_perm(hi, lo, 0x07030501u);
    h[g+8] = __builtin_amdgcn_perm(hi, lo, 0x06020400u);
  }
#pragma unroll
  for (int g = 0; g < 8; ++g) {      // J=4
    int k = (g >> 2)*8 + (g & 3);
    unsigned A = h[k], B = h[k+4];
    h[k]   = BSEL(0x0F0F0F0Fu, B >> 4, A);
    h[k+4] = BSEL(0xF0F0F0F0u, A << 4, B);
  }
#pragma unroll
  for (int g = 0; g < 8; ++g) {      // J=2
    int k = (g >> 1)*4 + (g & 1);
    unsigned A = h[k], B = h[k+2];
    h[k]   = BSEL(0x33333333u, B >> 2, A);
    h[k+2] = BSEL(0xCCCCCCCCu, A << 2, B);
  }
#pragma unroll
  for (int g = 0; g < 8; ++g) {      // J=1
    int k = g*2;
    unsigned A = h[k], B = h[k+1];
    h[k]   = BSEL(0x55555555u, B >> 1, A);
    h[k+1] = BSEL(0xAAAAAAAAu, A << 1, B);
  }

  // radix select on bits 30..16 (h[1..15]); SALU alive-count; guards from 7
  unsigned alive = 0xFFFFFFFFu, below = 0u;
  int rem = KNN, ca = 2048;
#pragma unroll
  for (int i = 1; i <= 6; ++i) {
    unsigned zeros = BSEL(h[i], 0u, alive);
    int c0 = wave_isum_bcast(__popc(zeros));
    if (c0 >= rem) { alive = zeros; ca = c0; }
    else { rem -= c0; below |= zeros; alive &= h[i]; ca -= c0; }
  }
#pragma unroll
  for (int i = 7; i <= 15; ++i) {
    if (ca != rem) {
      unsigned zeros = BSEL(h[i], 0u, alive);
      int c0 = wave_isum_bcast(__popc(zeros));
      if (c0 >= rem) { alive = zeros; ca = c0; }
      else { rem -= c0; below |= zeros; alive &= h[i]; ca -= c0; }
    }
  }
  unsigned sel;
  if (__builtin_expect(ca == rem, 1)) {
    sel = below | alive;
  } else {
    // unresolved on hi bits: transpose the lo half -> l[i] = plane of bit (15-i)
#pragma unroll
    for (int g = 0; g < 8; ++g) {    // J=8
      unsigned hi = l[g], lo = l[g+8];
      l[g]   = __builtin_amdgcn_perm(hi, lo, 0x07030501u);
      l[g+8] = __builtin_amdgcn_perm(hi, lo, 0x06020400u);
    }
#pragma unroll
    for (int g = 0; g < 8; ++g) {    // J=4
      int k = (g >> 2)*8 + (g & 3);
      unsigned A = l[k], B = l[k+4];
      l[k]   = BSEL(0x0F0F0F0Fu, B >> 4, A);
      l[k+4] = BSEL(0xF0F0F0F0u, A << 4, B);
    }
#pragma unroll
    for (int g = 0; g < 8; ++g) {    // J=2
      int k = (g >> 1)*4 + (g & 1);
      unsigned A = l[k], B = l[k+2];
      l[k]   = BSEL(0x33333333u, B >> 2, A);
      l[k+2] = BSEL(0xCCCCCCCCu, A << 2, B);
    }
#pragma unroll
    for (int g = 0; g < 8; ++g) {    // J=1
      int k = g*2;
      unsigned A = l[k], B = l[k+1];
      l[k]   = BSEL(0x55555555u, B >> 1, A);
      l[k+1] = BSEL(0xAAAAAAAAu, A << 1, B);
    }
#pragma unroll
    for (int i = 0; i < 16; ++i) {   // extend radix onto bits 15..0
      if (ca != rem) {
        unsigned zeros = BSEL(l[i], 0u, alive);
        int c0 = wave_isum_bcast(__popc(zeros));
        if (c0 >= rem) { alive = zeros; ca = c0; }
        else { rem -= c0; below |= zeros; alive &= l[i]; ca -= c0; }
      }
    }
    sel = below;
    if (ca == rem) {
      sel |= alive;
    } else {
      // bit-identical distances: smallest j = v*64 + lane -> v-major, lane-minor
      for (int v = 0; v < 32; ++v) {
        if (rem <= 0) break;
        bool mine = (alive >> v) & 1;
        unsigned long long mb = __ballot(mine);
        int c = __popcll(mb);
        if (c <= rem) { if (mine) sel |= 1u << v; rem -= c; }
        else {
          if (mine && (int)__popcll(mb & ((1ull << lane) - 1)) < rem) sel |= 1u << v;
          rem = 0;
        }
      }
    }
  }

  // gather: sum/sumsq/min of q_j over selected (scalar chunk reads, ~2-way max)
  float w3[CH1], w4[CH1], w5[CH1];
#pragma unroll
  for (int c = 0; c < CH1; ++c) { w3[c]=W1[3*CH1+c]; w4[c]=W1[4*CH1+c]; w5[c]=W1[5*CH1+c]; }
  float sq_[CH1], sqq[CH1], mn[CH1];
#pragma unroll
  for (int c = 0; c < CH1; ++c) { sq_[c] = 0.f; sqq[c] = 0.f; mn[c] = INFINITY; }
  unsigned m = sel;
  while (m) {
    int v = __builtin_ctz(m); m &= m - 1;
    int idx = (((v >> 2) << 6) | lane) * 4 + (v & 3);
    float px_ = Xs[idx], py_ = Ys[idx], pz_ = Zs[idx];
#pragma unroll
    for (int c = 0; c < CH1; ++c) {
      float qv = px_*w3[c] + py_*w4[c] + pz_*w5[c];   // contraction OK here
      sq_[c] += qv; sqq[c] += qv*qv; mn[c] = fminf(mn[c], qv);
    }
  }

  // p_i for this query (uniform across lanes)
  float pv[CH1];
#pragma unroll
  for (int c = 0; c < CH1; ++c) {
    float qv = qx*w3[c] + qy*w4[c] + qz*w5[c];
    pv[c] = b1[c] + qx*W1[c] + qy*W1[CH1+c] + qz*W1[2*CH1+c] + qv;
  }

#pragma unroll
  for (int c = 0; c < CH1; ++c) {
    float s  = wave_fsum63(sq_[c]);
    float s2 = wave_fsum63(sqq[c]);
    float mm = wave_fmin63(mn[c]);
    if (lane == 63) {
      minq[qi*CH1 + c] = mm;
      red[c][w]       = fmaf(32.f, pv[c], -s);                            // sum_k (p-q)
      red[CH1 + c][w] = fmaf(32.f, pv[c]*pv[c], fmaf(-2.f*pv[c], s, s2)); // sum_k (p-q)^2
    }
  }
  if (lane == 0) {
#pragma unroll
    for (int c = 0; c < CH1; ++c) pout[qi*CH1 + c] = pv[c];
  }
  __syncthreads();
  if (threadIdx.x < 12) {
    float s = 0.f;
#pragma unroll
    for (int ww2 = 0; ww2 < QPB; ++ww2) s += red[threadIdx.x][ww2];
    atomicAdd(s1rep + (blockIdx.x & 7) * 12 + threadIdx.x, (double)s);
  }
}

// stage2: derive sc1 (block 0 publishes), compute me per query, accumulate the
// 27 BN2 moments (Sme[6] + upper-tri M[21]); y-stats derive from them linearly.
__global__ __launch_bounds__(256) void stage2_kernel(const float* __restrict__ p,
                                                     const float* __restrict__ minq,
                                                     const double* __restrict__ s1rep,
                                                     const float* __restrict__ gamma1,
                                                     const float* __restrict__ beta1,
                                                     float* __restrict__ sc1g,
                                                     double* __restrict__ stats2L) {
  __shared__ double tot1[12];
  __shared__ float sc1s[12];
  __shared__ float acc[4][27];
  const int t = threadIdx.x;
  if (t < 12) {
    double s = 0.0;
#pragma unroll
    for (int r = 0; r < 8; ++r) s += s1rep[r*12 + t];
    tot1[t] = s;
  }
  __syncthreads();
  if (t < CH1) {
    double cnt  = (double)NB * NP * KNN;
    double mean = tot1[t] / cnt;
    double var  = tot1[CH1 + t] / cnt - mean * mean;
    float scale = gamma1[t] / sqrtf((float)var + BN_EPS);
    sc1s[t] = scale; sc1s[CH1 + t] = beta1[t] - (float)mean * scale;
  }
  __syncthreads();
  if (blockIdx.x == 0 && t < 12) sc1g[t] = sc1s[t];

  const int qi = blockIdx.x * 256 + t;
  const int w = t >> 6, lane = t & 63;
  float me[CH1];
#pragma unroll
  for (int c = 0; c < CH1; ++c) {
    float v = fmaf(sc1s[c], p[qi*CH1 + c] - minq[qi*CH1 + c], sc1s[CH1 + c]);
    me[c] = v > 0.f ? v : expm1f(v);
  }
  float vals[27];
#pragma unroll
  for (int c = 0; c < CH1; ++c) vals[c] = me[c];
  {
    int id = 6;
#pragma unroll
    for (int c = 0; c < CH1; ++c)
#pragma unroll
      for (int d = c; d < CH1; ++d) { vals[id] = me[c]*me[d]; ++id; }
  }
#pragma unroll
  for (int k = 0; k < 27; ++k) {
    float s = wave_fsum63(vals[k]);
    if (lane == 63) acc[w][k] = s;
  }
  __syncthreads();
  if (t < 27)
    atomicAdd(stats2L + (blockIdx.x & 3) * 27 + t,
              (double)((acc[0][t] + acc[1][t]) + (acc[2][t] + acc[3][t])));
}

// final: derive sc2 per block from the 27 moments, recompute y, BN2 + ELU.
__global__ __launch_bounds__(256) void out_kernel(const float* __restrict__ p,
                                                  const float* __restrict__ minq,
                                                  const float* __restrict__ sc1,
                                                  const float* __restrict__ W2,
                                                  const float* __restrict__ b2,
                                                  const double* __restrict__ stats2L,
                                                  const float* __restrict__ gamma2,
                                                  const float* __restrict__ beta2,
                                                  float* __restrict__ out) {
  __shared__ float m2[27];
  __shared__ float me_lds[8][CH1];
  __shared__ float s2s[CH2], s2h[CH2];
  const int t = threadIdx.x;
  if (t < 27)
    m2[t] = (float)(((stats2L[t] + stats2L[27+t]) + (stats2L[54+t] + stats2L[81+t])));
  const int qbase = blockIdx.x * 8;
  if (t >= 64 && t < 112) {
    int qs = (t - 64) / 6, c = (t - 64) % 6;
    int qi = qbase + qs;
    float v = fmaf(sc1[c], p[qi*CH1 + c] - minq[qi*CH1 + c], sc1[CH1 + c]);
    me_lds[qs][c] = v > 0.f ? v : expm1f(v);
  }
  __syncthreads();
  if (t < CH2) {
    float wv[CH1];
#pragma unroll
    for (int c = 0; c < CH1; ++c) wv[c] = W2[c*CH2 + t];
    float sy = 0.f;
#pragma unroll
    for (int c = 0; c < CH1; ++c) sy = fmaf(wv[c], m2[c], sy);
    float sy2 = 0.f;
    {
      int id = 6;
#pragma unroll
      for (int c = 0; c < CH1; ++c)
#pragma unroll
        for (int d = c; d < CH1; ++d) {
          float coef = (c == d) ? wv[c]*wv[c] : 2.f*wv[c]*wv[d];
          sy2 = fmaf(coef, m2[id], sy2); ++id;
        }
    }
    const double N = (double)NB * NP;
    double bo   = (double)b2[t];
    double mean = ((double)sy + N*bo) / N;
    double Ey2  = ((double)sy2 + 2.0*bo*(double)sy + N*bo*bo) / N;
    double var  = Ey2 - mean*mean;
    float scale = gamma2[t] / sqrtf((float)var + BN_EPS);
    s2s[t] = scale; s2h[t] = beta2[t] - (float)mean * scale;
  }
  __syncthreads();
  const int qs = t >> 5, o = t & 31;
  const int qi = qbase + qs;
  float y = b2[o];
#pragma unroll
  for (int c = 0; c < CH1; ++c) y = fmaf(me_lds[qs][c], W2[c*CH2 + o], y);
  float r = fmaf(s2s[o], y, s2h[o]);
  out[(size_t)qi*CH2 + o] = r > 0.f ? r : expm1f(r);
}

extern "C" void kernel_launch(void* const* d_in, const int* in_sizes, int n_in,
                              void* d_out, int out_size, void* d_ws, size_t ws_size,
                              hipStream_t stream) {
  const float* x      = (const float*)d_in[0];
  const float* W1     = (const float*)d_in[1];
  const float* b1     = (const float*)d_in[2];
  const float* gamma1 = (const float*)d_in[3];
  const float* beta1  = (const float*)d_in[4];
  const float* W2     = (const float*)d_in[5];
  const float* b2     = (const float*)d_in[6];
  const float* gamma2 = (const float*)d_in[7];
  const float* beta2  = (const float*)d_in[8];
  float* out = (float*)d_out;
  char* ws = (char*)d_ws;

  double* s1rep   = (double*)(ws + OFF_S1REP);
  double* stats2L = (double*)(ws + OFF_STATS2L);
  float* sc1  = (float*)(ws + OFF_SC1);
  float* p    = (float*)(ws + OFF_P);
  float* minq = (float*)(ws + OFF_MINQ);

  hipMemsetAsync(ws, 0, 1664, stream);  // zero BN stat accumulators

  knn_kernel   <<<dim3(NBLK),       dim3(512), 0, stream>>>(x, W1, b1, p, minq, s1rep);
  stage2_kernel<<<dim3(NB*NP/256),  dim3(256), 0, stream>>>(p, minq, s1rep, gamma1, beta1,
                                                            sc1, stats2L);
  out_kernel   <<<dim3(NB*NP/8),    dim3(256), 0, stream>>>(p, minq, sc1, W2, b2,
                                                            stats2L, gamma2, beta2, out);
}